// Round 10
// baseline (170.911 us; speedup 1.0000x reference)
//
#include <hip/hip_runtime.h>

#define NN 100000
#define NE 5000000
#define NB 16
#define NDM 512

#define RPB 1024                             // rows per destination bucket
#define NBUCKET 98                           // ceil(NN/RPB), 98*1024 = 100352
#define CAP 55296                            // per-bucket capacity (mean 51020 + 19 sigma)
#define CHUNK 8192                           // edges per scatter block
#define NCHUNK ((NE + CHUNK - 1) / CHUNK)    // 611 (last chunk 2880, %4==0)
#define SUB 16                               // sub-slices per bucket in hops
#define NWAVE 16                             // waves per 1024-thread block

// u0[dm_cols[d]] += dmv[d]*fc_w[d]; cursor[b] = b*CAP
__global__ void setup(const float* __restrict__ dmv, const int* __restrict__ dmc,
                      const float* __restrict__ fcw,
                      float* __restrict__ u0, int* __restrict__ cursor) {
    int t = threadIdx.x;                     // 512
    if (t < NDM) atomicAdd(&u0[dmc[t]], dmv[t] * fcw[t]);
    if (t < NBUCKET) cursor[t] = t * CAP;
}

// single-pass: per-wave histogram -> per-(wave,bucket) global cursors (in-place)
// -> scatter with wave-local rank atomics, hop-1 fused.
// packed[pos] = ((dst&1023)<<17 | src, w_bits)
__global__ void scatter_fused(const int* __restrict__ er, const int* __restrict__ ec,
                              const float* __restrict__ ew,
                              const float* __restrict__ u0, float* __restrict__ u1,
                              int* __restrict__ cursor, int2* __restrict__ packed) {
    __shared__ int hist[NWAVE][NBUCKET];
    __shared__ __align__(16) int sdst[CHUNK];   // staged ec values (32KB)
    int tid = threadIdx.x;                   // 1024
    int wv = tid >> 6;
    for (int k = tid; k < NWAVE * NBUCKET; k += 1024) hist[k / NBUCKET][k % NBUCKET] = 0;
    __syncthreads();
    int base = blockIdx.x * CHUNK;
    int n = min(CHUNK, NE - base);
    const int4* ec4 = (const int4*)(ec + base);
    // phase 1: stage ec + per-wave histogram
    for (int k = tid; k < (n >> 2); k += 1024) {
        int4 c = ec4[k];
        ((int4*)sdst)[k] = c;
        atomicAdd(&hist[wv][c.x >> 10], 1);
        atomicAdd(&hist[wv][c.y >> 10], 1);
        atomicAdd(&hist[wv][c.z >> 10], 1);
        atomicAdd(&hist[wv][c.w >> 10], 1);
    }
    __syncthreads();
    // reserve per-bucket region once; turn hist[w][b] into global write cursors
    for (int b = tid; b < NBUCKET; b += 1024) {
        int pre[NWAVE];
        int c = 0;
        #pragma unroll
        for (int w = 0; w < NWAVE; ++w) { pre[w] = c; c += hist[w][b]; }
        int gb = c ? atomicAdd(&cursor[b], c) : 0;
        #pragma unroll
        for (int w = 0; w < NWAVE; ++w) hist[w][b] = gb + pre[w];
    }
    __syncthreads();
    // phase 2: scatter via wave-local cursors + fused hop-1
    const int4*   er4 = (const int4*)(er + base);
    const float4* ew4 = (const float4*)(ew + base);
    for (int k = tid; k < (n >> 2); k += 1024) {
        int4 r = er4[k];
        float4 w = ew4[k];
        int k4 = 4 * k;
        int d, pos;
        float a;
        d = sdst[k4];     pos = atomicAdd(&hist[wv][d >> 10], 1);
        packed[pos] = make_int2(((d & 1023) << 17) | r.x, __float_as_int(w.x));
        a = u0[r.x]; if (a != 0.f) atomicAdd(&u1[d], w.x * a);
        d = sdst[k4 + 1]; pos = atomicAdd(&hist[wv][d >> 10], 1);
        packed[pos] = make_int2(((d & 1023) << 17) | r.y, __float_as_int(w.y));
        a = u0[r.y]; if (a != 0.f) atomicAdd(&u1[d], w.y * a);
        d = sdst[k4 + 2]; pos = atomicAdd(&hist[wv][d >> 10], 1);
        packed[pos] = make_int2(((d & 1023) << 17) | r.z, __float_as_int(w.z));
        a = u0[r.z]; if (a != 0.f) atomicAdd(&u1[d], w.z * a);
        d = sdst[k4 + 3]; pos = atomicAdd(&hist[wv][d >> 10], 1);
        packed[pos] = make_int2(((d & 1023) << 17) | r.w, __float_as_int(w.w));
        a = u0[r.w]; if (a != 0.f) atomicAdd(&u1[d], w.w * a);
    }
}

// sorted hop: LDS-accumulate 1024 rows per bucket, ILP packed reads,
// flush with consecutive-lane global atomics.
__global__ void spmv_sorted(const int* __restrict__ cursor,
                            const int2* __restrict__ packed,
                            const float* __restrict__ wc, float* __restrict__ wn) {
    __shared__ float acc[RPB];
    int bucket = blockIdx.x >> 4;            // / SUB
    int sub = blockIdx.x & (SUB - 1);
    int t = threadIdx.x;                     // 256
    #pragma unroll
    for (int k = 0; k < 4; ++k) acc[t + 256 * k] = 0.f;
    __syncthreads();
    int s = bucket * CAP;
    int e = cursor[bucket];                  // region end after reservation
    int cnt = e - s;
    int slice = (cnt + SUB - 1) >> 4;
    int mys = s + sub * slice;
    int mye = min(mys + slice, e);
    int i = mys + t;
    for (; i + 256 < mye; i += 512) {
        int2 p0 = packed[i];
        int2 p1 = packed[i + 256];
        float v0 = __int_as_float(p0.y) * wc[p0.x & 0x1FFFF];
        float v1 = __int_as_float(p1.y) * wc[p1.x & 0x1FFFF];
        if (v0 != 0.f) atomicAdd(&acc[p0.x >> 17], v0);
        if (v1 != 0.f) atomicAdd(&acc[p1.x >> 17], v1);
    }
    if (i < mye) {
        int2 p = packed[i];
        float v = __int_as_float(p.y) * wc[p.x & 0x1FFFF];
        if (v != 0.f) atomicAdd(&acc[p.x >> 17], v);
    }
    __syncthreads();
    #pragma unroll
    for (int k = 0; k < 4; ++k) {
        int row = bucket * RPB + t + 256 * k;
        float a = acc[t + 256 * k];
        if (a != 0.f && row < NN) atomicAdd(&wn[row], a);
    }
}

// tiled final dot: 196 blocks x 512-row tiles
__global__ void final_dot(const float* __restrict__ x, const float* __restrict__ tw,
                          const float* __restrict__ tb, const int* __restrict__ ct,
                          const float* __restrict__ u,
                          float* __restrict__ acc_out) {
    __shared__ float s[512];
    __shared__ float sred[256][4];
    __shared__ float sbias[4];
    int tid = threadIdx.x;          // 256
    int base = blockIdx.x * 512;
    int nrows = min(512, NN - base);
    float accb = 0.f;
    for (int r = tid; r < nrows; r += 256) {
        int n = base + r;
        float un = u[n];
        int t = ct[n];
        s[r] = un * tw[t];
        accb = fmaf(un, tb[t], accb);
    }
    __syncthreads();
    float a0 = 0.f, a1 = 0.f, a2 = 0.f, a3 = 0.f;
    int j = (tid & 3) * 4;
    for (int r = tid >> 2; r < nrows; r += 64) {
        float4 xv = *(const float4*)&x[(size_t)(base + r) * NB + j];
        float sv = s[r];
        a0 = fmaf(sv, xv.x, a0);
        a1 = fmaf(sv, xv.y, a1);
        a2 = fmaf(sv, xv.z, a2);
        a3 = fmaf(sv, xv.w, a3);
    }
    sred[tid][0] = a0; sred[tid][1] = a1; sred[tid][2] = a2; sred[tid][3] = a3;
    for (int off = 32; off; off >>= 1) accb += __shfl_down(accb, off);
    if ((tid & 63) == 0) sbias[tid >> 6] = accb;
    __syncthreads();
    if (tid < 16) {
        int q = tid >> 2, k = tid & 3;
        float sum = 0.f;
        for (int i = 0; i < 64; ++i) sum += sred[q + 4 * i][k];
        atomicAdd(&acc_out[tid], sum);
    }
    if (tid == 16)
        atomicAdd(&acc_out[16], sbias[0] + sbias[1] + sbias[2] + sbias[3]);
}

__global__ void finalize(const float* __restrict__ acc, const float* __restrict__ fcb,
                         float* __restrict__ out) {
    int b = threadIdx.x;
    if (b < NB) out[b] = acc[b] + acc[16] + fcb[0];
}

extern "C" void kernel_launch(void* const* d_in, const int* in_sizes, int n_in,
                              void* d_out, int out_size, void* d_ws, size_t ws_size,
                              hipStream_t stream) {
    const float* x   = (const float*)d_in[0];
    const float* tw  = (const float*)d_in[1];
    const float* tb  = (const float*)d_in[2];
    const float* ew  = (const float*)d_in[3];
    const float* dmv = (const float*)d_in[4];
    const float* fcw = (const float*)d_in[5];
    const float* fcb = (const float*)d_in[6];
    const int* ct  = (const int*)d_in[7];
    const int* er  = (const int*)d_in[8];
    const int* ec  = (const int*)d_in[9];
    const int* dmc = (const int*)d_in[10];
    float* out = (float*)d_out;

    // ws: [zero-region: u0..u4 (5*NN) | acc(32)] cursor(128) packed(98*CAP*8 = 43.4MB)
    char* ws = (char*)d_ws;
    float* u   = (float*)ws;                       // u + k*NN, k=0..4
    float* acc = u + 5 * (size_t)NN;
    size_t zero_bytes = (5 * (size_t)NN + 32) * 4;
    ws += zero_bytes;
    int* cursor = (int*)ws;         ws += 128 * 4;
    ws = (char*)(((uintptr_t)ws + 15) & ~(uintptr_t)15);
    int2* packed = (int2*)ws;       // NBUCKET * CAP * 8B

    // zero all hop buffers + acc (cursor is set by setup)
    hipMemsetAsync(u, 0, zero_bytes, stream);

    // u0 = v; cursor[b] = b*CAP
    setup<<<1, 512, 0, stream>>>(dmv, dmc, fcw, u, cursor);

    // one pass over edges: bucket-sort into packed + fused hop 1 (u0 -> u1)
    scatter_fused<<<NCHUNK, 1024, 0, stream>>>(er, ec, ew, u, u + NN, cursor, packed);

    // hops 2..4 on sorted packed edges
    for (int l = 1; l < 4; ++l) {
        spmv_sorted<<<NBUCKET * SUB, 256, 0, stream>>>(cursor, packed,
                                                       u + (size_t)l * NN,
                                                       u + (size_t)(l + 1) * NN);
    }

    // out[b] = sum_n u4[n]*(tw[ct[n]]*x[n,b] + tb[ct[n]]) + fcb
    final_dot<<<(NN + 511) / 512, 256, 0, stream>>>(x, tw, tb, ct, u + 4 * (size_t)NN, acc);
    finalize<<<1, 64, 0, stream>>>(acc, fcb, out);
}

// Round 11
// 158.540 us; speedup vs baseline: 1.0780x; 1.0780x over previous
//
#include <hip/hip_runtime.h>

#define NN 100000
#define NE 5000000
#define NB 16
#define NDM 512

#define RPB 1024                             // rows per destination bucket
#define NBUCKET 98                           // ceil(NN/RPB), 98*1024 = 100352
#define CAP 55296                            // per-bucket capacity (mean 51020 + 19 sigma)
#define CHUNK 8192                           // edges per scatter block
#define NCHUNK ((NE + CHUNK - 1) / CHUNK)    // 611 (last chunk 2880, %4==0)
#define SUB 16                               // sub-slices per bucket in hops
#define NWAVE 16                             // waves per 1024-thread block

// u0[dm_cols[d]] += dmv[d]*fc_w[d]; cursor[b] = b*CAP
__global__ void setup(const float* __restrict__ dmv, const int* __restrict__ dmc,
                      const float* __restrict__ fcw,
                      float* __restrict__ u0, int* __restrict__ cursor) {
    int t = threadIdx.x;                     // 512
    if (t < NDM) atomicAdd(&u0[dmc[t]], dmv[t] * fcw[t]);
    if (t < NBUCKET) cursor[t] = t * CAP;
}

// single pass over edges: per-wave histogram -> block-local sorted assembly in
// LDS -> coalesced full-line streaming to per-bucket global regions.
// hop-1 (u1[ec] += ew*u0[er], source-sparse) fused into phase 2.
// packed[pos] = ((dst&1023)<<17 | src, w_bits)
__global__ void scatter_fused(const int* __restrict__ er, const int* __restrict__ ec,
                              const float* __restrict__ ew,
                              const float* __restrict__ u0, float* __restrict__ u1,
                              int* __restrict__ cursor, int2* __restrict__ packed) {
    __shared__ int hist[NWAVE][NBUCKET];        // -> per-(wave,bucket) local cursors
    __shared__ __align__(16) int sdst[CHUNK];   // staged ec (32KB)
    __shared__ int2 pval[CHUNK];                // block-sorted packed entries (64KB)
    __shared__ unsigned char sbk[CHUNK];        // bucket id per sorted slot (8KB)
    __shared__ int lbloc[NBUCKET];              // block-local bucket start
    __shared__ int gbase[NBUCKET];              // global region base for this block
    __shared__ int ctot[NBUCKET];               // block totals per bucket
    int tid = threadIdx.x;                      // 1024
    int wv = tid >> 6;
    for (int k = tid; k < NWAVE * NBUCKET; k += 1024) hist[k / NBUCKET][k % NBUCKET] = 0;
    __syncthreads();
    int base = blockIdx.x * CHUNK;
    int n = min(CHUNK, NE - base);
    const int4* ec4 = (const int4*)(ec + base);
    // phase 1: stage ec + per-wave histogram
    for (int k = tid; k < (n >> 2); k += 1024) {
        int4 c = ec4[k];
        ((int4*)sdst)[k] = c;
        atomicAdd(&hist[wv][c.x >> 10], 1);
        atomicAdd(&hist[wv][c.y >> 10], 1);
        atomicAdd(&hist[wv][c.z >> 10], 1);
        atomicAdd(&hist[wv][c.w >> 10], 1);
    }
    __syncthreads();
    // per-bucket totals + one global reservation per bucket; keep wave prefixes
    int pre[NWAVE];
    int myb = -1, myc = 0;
    if (tid < NBUCKET) {
        myb = tid;
        int c = 0;
        #pragma unroll
        for (int w = 0; w < NWAVE; ++w) { pre[w] = c; c += hist[w][myb]; }
        myc = c;
        ctot[myb] = c;
        gbase[myb] = c ? atomicAdd(&cursor[myb], c) : 0;
    }
    __syncthreads();
    // block-local bucket prefix (serial, 98 iters, negligible)
    if (tid == 0) {
        int run = 0;
        for (int b = 0; b < NBUCKET; ++b) { lbloc[b] = run; run += ctot[b]; }
    }
    __syncthreads();
    // finalize per-(wave,bucket) local cursors
    if (myb >= 0) {
        int lb = lbloc[myb];
        #pragma unroll
        for (int w = 0; w < NWAVE; ++w) hist[w][myb] = lb + pre[w];
    }
    __syncthreads();
    // phase 2: sort into LDS (wave-local rank atomics) + fused hop-1
    const int4*   er4 = (const int4*)(er + base);
    const float4* ew4 = (const float4*)(ew + base);
    for (int k = tid; k < (n >> 2); k += 1024) {
        int4 r = er4[k];
        float4 w = ew4[k];
        int k4 = 4 * k;
        int d, bk, lp;
        float a;
        d = sdst[k4];     bk = d >> 10; lp = atomicAdd(&hist[wv][bk], 1);
        pval[lp] = make_int2(((d & 1023) << 17) | r.x, __float_as_int(w.x));
        sbk[lp] = (unsigned char)bk;
        a = u0[r.x]; if (a != 0.f) atomicAdd(&u1[d], w.x * a);
        d = sdst[k4 + 1]; bk = d >> 10; lp = atomicAdd(&hist[wv][bk], 1);
        pval[lp] = make_int2(((d & 1023) << 17) | r.y, __float_as_int(w.y));
        sbk[lp] = (unsigned char)bk;
        a = u0[r.y]; if (a != 0.f) atomicAdd(&u1[d], w.y * a);
        d = sdst[k4 + 2]; bk = d >> 10; lp = atomicAdd(&hist[wv][bk], 1);
        pval[lp] = make_int2(((d & 1023) << 17) | r.z, __float_as_int(w.z));
        sbk[lp] = (unsigned char)bk;
        a = u0[r.z]; if (a != 0.f) atomicAdd(&u1[d], w.z * a);
        d = sdst[k4 + 3]; bk = d >> 10; lp = atomicAdd(&hist[wv][bk], 1);
        pval[lp] = make_int2(((d & 1023) << 17) | r.w, __float_as_int(w.w));
        sbk[lp] = (unsigned char)bk;
        a = u0[r.w]; if (a != 0.f) atomicAdd(&u1[d], w.w * a);
    }
    __syncthreads();
    // phase 3: stream sorted segment out; consecutive lanes -> consecutive addrs
    for (int i = tid; i < n; i += 1024) {
        int bk = sbk[i];
        packed[gbase[bk] + (i - lbloc[bk])] = pval[i];
    }
}

// sorted hop: LDS-accumulate 1024 rows per bucket, ILP packed reads,
// flush with consecutive-lane global atomics.
__global__ void spmv_sorted(const int* __restrict__ cursor,
                            const int2* __restrict__ packed,
                            const float* __restrict__ wc, float* __restrict__ wn) {
    __shared__ float acc[RPB];
    int bucket = blockIdx.x >> 4;            // / SUB
    int sub = blockIdx.x & (SUB - 1);
    int t = threadIdx.x;                     // 256
    #pragma unroll
    for (int k = 0; k < 4; ++k) acc[t + 256 * k] = 0.f;
    __syncthreads();
    int s = bucket * CAP;
    int e = cursor[bucket];                  // region end after reservation
    int cnt = e - s;
    int slice = (cnt + SUB - 1) >> 4;
    int mys = s + sub * slice;
    int mye = min(mys + slice, e);
    int i = mys + t;
    for (; i + 256 < mye; i += 512) {
        int2 p0 = packed[i];
        int2 p1 = packed[i + 256];
        float v0 = __int_as_float(p0.y) * wc[p0.x & 0x1FFFF];
        float v1 = __int_as_float(p1.y) * wc[p1.x & 0x1FFFF];
        if (v0 != 0.f) atomicAdd(&acc[p0.x >> 17], v0);
        if (v1 != 0.f) atomicAdd(&acc[p1.x >> 17], v1);
    }
    if (i < mye) {
        int2 p = packed[i];
        float v = __int_as_float(p.y) * wc[p.x & 0x1FFFF];
        if (v != 0.f) atomicAdd(&acc[p.x >> 17], v);
    }
    __syncthreads();
    #pragma unroll
    for (int k = 0; k < 4; ++k) {
        int row = bucket * RPB + t + 256 * k;
        float a = acc[t + 256 * k];
        if (a != 0.f && row < NN) atomicAdd(&wn[row], a);
    }
}

// tiled final dot: 196 blocks x 512-row tiles
__global__ void final_dot(const float* __restrict__ x, const float* __restrict__ tw,
                          const float* __restrict__ tb, const int* __restrict__ ct,
                          const float* __restrict__ u,
                          float* __restrict__ acc_out) {
    __shared__ float s[512];
    __shared__ float sred[256][4];
    __shared__ float sbias[4];
    int tid = threadIdx.x;          // 256
    int base = blockIdx.x * 512;
    int nrows = min(512, NN - base);
    float accb = 0.f;
    for (int r = tid; r < nrows; r += 256) {
        int n = base + r;
        float un = u[n];
        int t = ct[n];
        s[r] = un * tw[t];
        accb = fmaf(un, tb[t], accb);
    }
    __syncthreads();
    float a0 = 0.f, a1 = 0.f, a2 = 0.f, a3 = 0.f;
    int j = (tid & 3) * 4;
    for (int r = tid >> 2; r < nrows; r += 64) {
        float4 xv = *(const float4*)&x[(size_t)(base + r) * NB + j];
        float sv = s[r];
        a0 = fmaf(sv, xv.x, a0);
        a1 = fmaf(sv, xv.y, a1);
        a2 = fmaf(sv, xv.z, a2);
        a3 = fmaf(sv, xv.w, a3);
    }
    sred[tid][0] = a0; sred[tid][1] = a1; sred[tid][2] = a2; sred[tid][3] = a3;
    for (int off = 32; off; off >>= 1) accb += __shfl_down(accb, off);
    if ((tid & 63) == 0) sbias[tid >> 6] = accb;
    __syncthreads();
    if (tid < 16) {
        int q = tid >> 2, k = tid & 3;
        float sum = 0.f;
        for (int i = 0; i < 64; ++i) sum += sred[q + 4 * i][k];
        atomicAdd(&acc_out[tid], sum);
    }
    if (tid == 16)
        atomicAdd(&acc_out[16], sbias[0] + sbias[1] + sbias[2] + sbias[3]);
}

__global__ void finalize(const float* __restrict__ acc, const float* __restrict__ fcb,
                         float* __restrict__ out) {
    int b = threadIdx.x;
    if (b < NB) out[b] = acc[b] + acc[16] + fcb[0];
}

extern "C" void kernel_launch(void* const* d_in, const int* in_sizes, int n_in,
                              void* d_out, int out_size, void* d_ws, size_t ws_size,
                              hipStream_t stream) {
    const float* x   = (const float*)d_in[0];
    const float* tw  = (const float*)d_in[1];
    const float* tb  = (const float*)d_in[2];
    const float* ew  = (const float*)d_in[3];
    const float* dmv = (const float*)d_in[4];
    const float* fcw = (const float*)d_in[5];
    const float* fcb = (const float*)d_in[6];
    const int* ct  = (const int*)d_in[7];
    const int* er  = (const int*)d_in[8];
    const int* ec  = (const int*)d_in[9];
    const int* dmc = (const int*)d_in[10];
    float* out = (float*)d_out;

    // ws: [zero-region: u0..u4 (5*NN) | acc(32)] cursor(128) packed(98*CAP*8 = 43.4MB)
    char* ws = (char*)d_ws;
    float* u   = (float*)ws;                       // u + k*NN, k=0..4
    float* acc = u + 5 * (size_t)NN;
    size_t zero_bytes = (5 * (size_t)NN + 32) * 4;
    ws += zero_bytes;
    int* cursor = (int*)ws;         ws += 128 * 4;
    ws = (char*)(((uintptr_t)ws + 15) & ~(uintptr_t)15);
    int2* packed = (int2*)ws;       // NBUCKET * CAP * 8B

    // zero all hop buffers + acc (cursor is set by setup)
    hipMemsetAsync(u, 0, zero_bytes, stream);

    // u0 = v; cursor[b] = b*CAP
    setup<<<1, 512, 0, stream>>>(dmv, dmc, fcw, u, cursor);

    // one pass over edges: bucket-sort into packed + fused hop 1 (u0 -> u1)
    scatter_fused<<<NCHUNK, 1024, 0, stream>>>(er, ec, ew, u, u + NN, cursor, packed);

    // hops 2..4 on sorted packed edges
    for (int l = 1; l < 4; ++l) {
        spmv_sorted<<<NBUCKET * SUB, 256, 0, stream>>>(cursor, packed,
                                                       u + (size_t)l * NN,
                                                       u + (size_t)(l + 1) * NN);
    }

    // out[b] = sum_n u4[n]*(tw[ct[n]]*x[n,b] + tb[ct[n]]) + fcb
    final_dot<<<(NN + 511) / 512, 256, 0, stream>>>(x, tw, tb, ct, u + 4 * (size_t)NN, acc);
    finalize<<<1, 64, 0, stream>>>(acc, fcb, out);
}

// Round 12
// 157.587 us; speedup vs baseline: 1.0846x; 1.0060x over previous
//
#include <hip/hip_runtime.h>

#define NN 100000
#define NE 5000000
#define NB 16
#define NDM 512

#define RPB 1024                             // rows per destination bucket
#define NBUCKET 98                           // ceil(NN/RPB), 98*1024 = 100352
#define CAP 55296                            // per-bucket capacity (mean 51020 + 19 sigma)
#define CHUNK 8192                           // edges per scatter block
#define NCHUNK ((NE + CHUNK - 1) / CHUNK)    // 611 (last chunk 2880, %4==0)
#define SUB 16                               // sub-slices per bucket in hops
#define NWAVE 16                             // waves per 1024-thread block

// u0[dm_cols[d]] += dmv[d]*fc_w[d]; cursor[b] = b*CAP
__global__ void setup(const float* __restrict__ dmv, const int* __restrict__ dmc,
                      const float* __restrict__ fcw,
                      float* __restrict__ u0, int* __restrict__ cursor) {
    int t = threadIdx.x;                     // 512
    if (t < NDM) atomicAdd(&u0[dmc[t]], dmv[t] * fcw[t]);
    if (t < NBUCKET) cursor[t] = t * CAP;
}

// single pass over edges: per-wave histogram -> block-local sorted assembly in
// LDS -> coalesced full-line streaming to per-bucket global regions.
// hop-1 (u1[ec] += ew*u0[er], source-sparse) fused into phase 2.
// LDS ~79.3KB -> 2 blocks/CU. packed[pos] = ((dst&1023)<<17 | src, w_bits)
__global__ void __launch_bounds__(1024, 8)
scatter_fused(const int* __restrict__ er, const int* __restrict__ ec,
              const float* __restrict__ ew,
              const float* __restrict__ u0, float* __restrict__ u1,
              int* __restrict__ cursor, int2* __restrict__ packed) {
    __shared__ int hist[NWAVE][NBUCKET];        // -> per-(wave,bucket) local cursors
    __shared__ int2 pval[CHUNK];                // block-sorted packed entries (64KB)
    __shared__ unsigned char sbk[CHUNK];        // bucket id per sorted slot (8KB)
    __shared__ int lbloc[NBUCKET];              // block-local bucket start
    __shared__ int gbase[NBUCKET];              // global region base for this block
    __shared__ int ctot[NBUCKET];               // block totals per bucket
    int tid = threadIdx.x;                      // 1024
    int wv = tid >> 6;
    for (int k = tid; k < NWAVE * NBUCKET; k += 1024) hist[k / NBUCKET][k % NBUCKET] = 0;
    __syncthreads();
    int base = blockIdx.x * CHUNK;
    int n = min(CHUNK, NE - base);
    const int4* ec4 = (const int4*)(ec + base);
    // phase 1: per-wave histogram of destination buckets
    for (int k = tid; k < (n >> 2); k += 1024) {
        int4 c = ec4[k];
        atomicAdd(&hist[wv][c.x >> 10], 1);
        atomicAdd(&hist[wv][c.y >> 10], 1);
        atomicAdd(&hist[wv][c.z >> 10], 1);
        atomicAdd(&hist[wv][c.w >> 10], 1);
    }
    __syncthreads();
    // per-bucket totals + one global reservation per bucket; keep wave prefixes
    int pre[NWAVE];
    int myb = -1;
    if (tid < NBUCKET) {
        myb = tid;
        int c = 0;
        #pragma unroll
        for (int w = 0; w < NWAVE; ++w) { pre[w] = c; c += hist[w][myb]; }
        ctot[myb] = c;
        gbase[myb] = c ? atomicAdd(&cursor[myb], c) : 0;
    }
    __syncthreads();
    // block-local bucket prefix (serial, 98 iters, negligible)
    if (tid == 0) {
        int run = 0;
        for (int b = 0; b < NBUCKET; ++b) { lbloc[b] = run; run += ctot[b]; }
    }
    __syncthreads();
    // finalize per-(wave,bucket) local cursors
    if (myb >= 0) {
        int lb = lbloc[myb];
        #pragma unroll
        for (int w = 0; w < NWAVE; ++w) hist[w][myb] = lb + pre[w];
    }
    __syncthreads();
    // phase 2: sort into LDS (wave-local rank atomics) + fused hop-1.
    // ec re-read from global (L2-hot from phase 1).
    const int4*   er4 = (const int4*)(er + base);
    const float4* ew4 = (const float4*)(ew + base);
    for (int k = tid; k < (n >> 2); k += 1024) {
        int4 c = ec4[k];
        int4 r = er4[k];
        float4 w = ew4[k];
        int d, bk, lp;
        float a;
        d = c.x; bk = d >> 10; lp = atomicAdd(&hist[wv][bk], 1);
        pval[lp] = make_int2(((d & 1023) << 17) | r.x, __float_as_int(w.x));
        sbk[lp] = (unsigned char)bk;
        a = u0[r.x]; if (a != 0.f) atomicAdd(&u1[d], w.x * a);
        d = c.y; bk = d >> 10; lp = atomicAdd(&hist[wv][bk], 1);
        pval[lp] = make_int2(((d & 1023) << 17) | r.y, __float_as_int(w.y));
        sbk[lp] = (unsigned char)bk;
        a = u0[r.y]; if (a != 0.f) atomicAdd(&u1[d], w.y * a);
        d = c.z; bk = d >> 10; lp = atomicAdd(&hist[wv][bk], 1);
        pval[lp] = make_int2(((d & 1023) << 17) | r.z, __float_as_int(w.z));
        sbk[lp] = (unsigned char)bk;
        a = u0[r.z]; if (a != 0.f) atomicAdd(&u1[d], w.z * a);
        d = c.w; bk = d >> 10; lp = atomicAdd(&hist[wv][bk], 1);
        pval[lp] = make_int2(((d & 1023) << 17) | r.w, __float_as_int(w.w));
        sbk[lp] = (unsigned char)bk;
        a = u0[r.w]; if (a != 0.f) atomicAdd(&u1[d], w.w * a);
    }
    __syncthreads();
    // phase 3: stream sorted segment out; consecutive lanes -> consecutive addrs
    for (int i = tid; i < n; i += 1024) {
        int bk = sbk[i];
        packed[gbase[bk] + (i - lbloc[bk])] = pval[i];
    }
}

// sorted hop: LDS-accumulate 1024 rows per bucket, ILP packed reads,
// flush with consecutive-lane global atomics.
__global__ void spmv_sorted(const int* __restrict__ cursor,
                            const int2* __restrict__ packed,
                            const float* __restrict__ wc, float* __restrict__ wn) {
    __shared__ float acc[RPB];
    int bucket = blockIdx.x >> 4;            // / SUB
    int sub = blockIdx.x & (SUB - 1);
    int t = threadIdx.x;                     // 256
    #pragma unroll
    for (int k = 0; k < 4; ++k) acc[t + 256 * k] = 0.f;
    __syncthreads();
    int s = bucket * CAP;
    int e = cursor[bucket];                  // region end after reservation
    int cnt = e - s;
    int slice = (cnt + SUB - 1) >> 4;
    int mys = s + sub * slice;
    int mye = min(mys + slice, e);
    int i = mys + t;
    for (; i + 256 < mye; i += 512) {
        int2 p0 = packed[i];
        int2 p1 = packed[i + 256];
        float v0 = __int_as_float(p0.y) * wc[p0.x & 0x1FFFF];
        float v1 = __int_as_float(p1.y) * wc[p1.x & 0x1FFFF];
        if (v0 != 0.f) atomicAdd(&acc[p0.x >> 17], v0);
        if (v1 != 0.f) atomicAdd(&acc[p1.x >> 17], v1);
    }
    if (i < mye) {
        int2 p = packed[i];
        float v = __int_as_float(p.y) * wc[p.x & 0x1FFFF];
        if (v != 0.f) atomicAdd(&acc[p.x >> 17], v);
    }
    __syncthreads();
    #pragma unroll
    for (int k = 0; k < 4; ++k) {
        int row = bucket * RPB + t + 256 * k;
        float a = acc[t + 256 * k];
        if (a != 0.f && row < NN) atomicAdd(&wn[row], a);
    }
}

// tiled final dot: 196 blocks x 512-row tiles
__global__ void final_dot(const float* __restrict__ x, const float* __restrict__ tw,
                          const float* __restrict__ tb, const int* __restrict__ ct,
                          const float* __restrict__ u,
                          float* __restrict__ acc_out) {
    __shared__ float s[512];
    __shared__ float sred[256][4];
    __shared__ float sbias[4];
    int tid = threadIdx.x;          // 256
    int base = blockIdx.x * 512;
    int nrows = min(512, NN - base);
    float accb = 0.f;
    for (int r = tid; r < nrows; r += 256) {
        int n = base + r;
        float un = u[n];
        int t = ct[n];
        s[r] = un * tw[t];
        accb = fmaf(un, tb[t], accb);
    }
    __syncthreads();
    float a0 = 0.f, a1 = 0.f, a2 = 0.f, a3 = 0.f;
    int j = (tid & 3) * 4;
    for (int r = tid >> 2; r < nrows; r += 64) {
        float4 xv = *(const float4*)&x[(size_t)(base + r) * NB + j];
        float sv = s[r];
        a0 = fmaf(sv, xv.x, a0);
        a1 = fmaf(sv, xv.y, a1);
        a2 = fmaf(sv, xv.z, a2);
        a3 = fmaf(sv, xv.w, a3);
    }
    sred[tid][0] = a0; sred[tid][1] = a1; sred[tid][2] = a2; sred[tid][3] = a3;
    for (int off = 32; off; off >>= 1) accb += __shfl_down(accb, off);
    if ((tid & 63) == 0) sbias[tid >> 6] = accb;
    __syncthreads();
    if (tid < 16) {
        int q = tid >> 2, k = tid & 3;
        float sum = 0.f;
        for (int i = 0; i < 64; ++i) sum += sred[q + 4 * i][k];
        atomicAdd(&acc_out[tid], sum);
    }
    if (tid == 16)
        atomicAdd(&acc_out[16], sbias[0] + sbias[1] + sbias[2] + sbias[3]);
}

__global__ void finalize(const float* __restrict__ acc, const float* __restrict__ fcb,
                         float* __restrict__ out) {
    int b = threadIdx.x;
    if (b < NB) out[b] = acc[b] + acc[16] + fcb[0];
}

extern "C" void kernel_launch(void* const* d_in, const int* in_sizes, int n_in,
                              void* d_out, int out_size, void* d_ws, size_t ws_size,
                              hipStream_t stream) {
    const float* x   = (const float*)d_in[0];
    const float* tw  = (const float*)d_in[1];
    const float* tb  = (const float*)d_in[2];
    const float* ew  = (const float*)d_in[3];
    const float* dmv = (const float*)d_in[4];
    const float* fcw = (const float*)d_in[5];
    const float* fcb = (const float*)d_in[6];
    const int* ct  = (const int*)d_in[7];
    const int* er  = (const int*)d_in[8];
    const int* ec  = (const int*)d_in[9];
    const int* dmc = (const int*)d_in[10];
    float* out = (float*)d_out;

    // ws: [zero-region: u0..u4 (5*NN) | acc(32)] cursor(128) packed(98*CAP*8 = 43.4MB)
    char* ws = (char*)d_ws;
    float* u   = (float*)ws;                       // u + k*NN, k=0..4
    float* acc = u + 5 * (size_t)NN;
    size_t zero_bytes = (5 * (size_t)NN + 32) * 4;
    ws += zero_bytes;
    int* cursor = (int*)ws;         ws += 128 * 4;
    ws = (char*)(((uintptr_t)ws + 15) & ~(uintptr_t)15);
    int2* packed = (int2*)ws;       // NBUCKET * CAP * 8B

    // zero all hop buffers + acc (cursor is set by setup)
    hipMemsetAsync(u, 0, zero_bytes, stream);

    // u0 = v; cursor[b] = b*CAP
    setup<<<1, 512, 0, stream>>>(dmv, dmc, fcw, u, cursor);

    // one pass over edges: bucket-sort into packed + fused hop 1 (u0 -> u1)
    scatter_fused<<<NCHUNK, 1024, 0, stream>>>(er, ec, ew, u, u + NN, cursor, packed);

    // hops 2..4 on sorted packed edges
    for (int l = 1; l < 4; ++l) {
        spmv_sorted<<<NBUCKET * SUB, 256, 0, stream>>>(cursor, packed,
                                                       u + (size_t)l * NN,
                                                       u + (size_t)(l + 1) * NN);
    }

    // out[b] = sum_n u4[n]*(tw[ct[n]]*x[n,b] + tb[ct[n]]) + fcb
    final_dot<<<(NN + 511) / 512, 256, 0, stream>>>(x, tw, tb, ct, u + 4 * (size_t)NN, acc);
    finalize<<<1, 64, 0, stream>>>(acc, fcb, out);
}

// Round 13
// 155.495 us; speedup vs baseline: 1.0991x; 1.0135x over previous
//
#include <hip/hip_runtime.h>

#define NN 100000
#define NE 5000000
#define NB 16
#define NDM 512

#define RPB 1024                             // rows per destination bucket
#define NBUCKET 98                           // ceil(NN/RPB), 98*1024 = 100352
#define CAP 55296                            // per-bucket capacity (mean 51020 + 19 sigma)
#define CHUNK 8192                           // edges per scatter block
#define NCHUNK ((NE + CHUNK - 1) / CHUNK)    // 611 (last chunk 2880, %4==0)
#define SUB 16                               // sub-slices per bucket in hops
#define NWAVE 16                             // waves per 1024-thread block

// u0[dm_cols[d]] += dmv[d]*fc_w[d]; cursor[b] = b*CAP
__global__ void setup(const float* __restrict__ dmv, const int* __restrict__ dmc,
                      const float* __restrict__ fcw,
                      float* __restrict__ u0, int* __restrict__ cursor) {
    int t = threadIdx.x;                     // 512
    if (t < NDM) atomicAdd(&u0[dmc[t]], dmv[t] * fcw[t]);
    if (t < NBUCKET) cursor[t] = t * CAP;
}

// single pass, register-held edges, ONE LDS atomic per edge:
// A: load+rank (atomic doubles as histogram) + fused hop-1
// B: rank -> LDS position (no atomic), C: coalesced stream-out.
// packed[pos] = ((dst&1023)<<17 | src, w_bits)
__global__ void __launch_bounds__(1024, 8)
scatter_fused(const int* __restrict__ er, const int* __restrict__ ec,
              const float* __restrict__ ew,
              const float* __restrict__ u0, float* __restrict__ u1,
              int* __restrict__ cursor, int2* __restrict__ packed) {
    __shared__ int hist[NWAVE][NBUCKET];        // counts -> per-(wave,bucket) starts
    __shared__ int2 pval[CHUNK];                // block-sorted packed entries (64KB)
    __shared__ unsigned char sbk[CHUNK];        // bucket id per sorted slot (8KB)
    __shared__ int lbloc[128];                  // block-local bucket starts (scan buf)
    __shared__ int gbase[NBUCKET];              // global region base for this block
    __shared__ int ctot[NBUCKET];               // block totals per bucket
    int tid = threadIdx.x;                      // 1024
    int wv = tid >> 6;
    for (int k = tid; k < NWAVE * NBUCKET; k += 1024) hist[k / NBUCKET][k % NBUCKET] = 0;
    __syncthreads();
    int base = blockIdx.x * CHUNK;
    int n = min(CHUNK, NE - base);
    int nq = n >> 2;
    const int4*   ec4 = (const int4*)(ec + base);
    const int4*   er4 = (const int4*)(er + base);
    const float4* ew4 = (const float4*)(ew + base);

    int2 ent[2][4];
    int  meta[2][4];
    // phase A: load once, rank via single LDS atomic, fused hop-1
    #pragma unroll
    for (int g = 0; g < 2; ++g) {
        int k = tid + g * 1024;
        if (k < nq) {
            int4 c = ec4[k];
            int4 r = er4[k];
            float4 w = ew4[k];
            int cc[4] = {c.x, c.y, c.z, c.w};
            int rr[4] = {r.x, r.y, r.z, r.w};
            float ww[4] = {w.x, w.y, w.z, w.w};
            #pragma unroll
            for (int j = 0; j < 4; ++j) {
                int d = cc[j];
                int bk = d >> 10;
                int lp = atomicAdd(&hist[wv][bk], 1);
                ent[g][j] = make_int2(((d & 1023) << 17) | rr[j], __float_as_int(ww[j]));
                meta[g][j] = (lp << 7) | bk;
                float a = u0[rr[j]];
                if (a != 0.f) atomicAdd(&u1[d], ww[j] * a);
            }
        }
    }
    __syncthreads();
    // per-bucket totals + one global reservation per bucket
    if (tid < NBUCKET) {
        int c = 0;
        #pragma unroll
        for (int w = 0; w < NWAVE; ++w) c += hist[w][tid];
        ctot[tid] = c;
        gbase[tid] = c ? atomicAdd(&cursor[tid], c) : 0;
    }
    __syncthreads();
    // parallel exclusive scan of ctot -> lbloc (128-wide, all threads sync)
    if (tid < 128) lbloc[tid] = (tid < NBUCKET) ? ctot[tid] : 0;
    __syncthreads();
    for (int off = 1; off < 128; off <<= 1) {
        int v = 0;
        if (tid < 128 && tid >= off) v = lbloc[tid - off];
        __syncthreads();
        if (tid < 128) lbloc[tid] += v;
        __syncthreads();
    }
    if (tid < NBUCKET) {
        int lb = lbloc[tid] - ctot[tid];     // exclusive
        lbloc[tid] = lb;
        // rewrite hist rows into per-(wave,bucket) start offsets
        int c = lb;
        #pragma unroll
        for (int w = 0; w < NWAVE; ++w) {
            int t = hist[w][tid];
            hist[w][tid] = c;
            c += t;
        }
    }
    __syncthreads();
    // phase B: place entries (no atomics)
    #pragma unroll
    for (int g = 0; g < 2; ++g) {
        int k = tid + g * 1024;
        if (k < nq) {
            #pragma unroll
            for (int j = 0; j < 4; ++j) {
                int m = meta[g][j];
                int bk = m & 127;
                int pos = hist[wv][bk] + (m >> 7);
                pval[pos] = ent[g][j];
                sbk[pos] = (unsigned char)bk;
            }
        }
    }
    __syncthreads();
    // phase C: stream sorted segment out; consecutive lanes -> consecutive addrs
    for (int i = tid; i < n; i += 1024) {
        int bk = sbk[i];
        packed[gbase[bk] + (i - lbloc[bk])] = pval[i];
    }
}

// sorted hop: LDS-accumulate 1024 rows per bucket, ILP-4 packed reads,
// flush with consecutive-lane global atomics.
__global__ void spmv_sorted(const int* __restrict__ cursor,
                            const int2* __restrict__ packed,
                            const float* __restrict__ wc, float* __restrict__ wn) {
    __shared__ float acc[RPB];
    int bucket = blockIdx.x >> 4;            // / SUB
    int sub = blockIdx.x & (SUB - 1);
    int t = threadIdx.x;                     // 256
    #pragma unroll
    for (int k = 0; k < 4; ++k) acc[t + 256 * k] = 0.f;
    __syncthreads();
    int s = bucket * CAP;
    int e = cursor[bucket];                  // region end after reservation
    int cnt = e - s;
    int slice = (cnt + SUB - 1) >> 4;
    int mys = s + sub * slice;
    int mye = min(mys + slice, e);
    int i = mys + t;
    for (; i + 768 < mye; i += 1024) {
        int2 p0 = packed[i];
        int2 p1 = packed[i + 256];
        int2 p2 = packed[i + 512];
        int2 p3 = packed[i + 768];
        float v0 = __int_as_float(p0.y) * wc[p0.x & 0x1FFFF];
        float v1 = __int_as_float(p1.y) * wc[p1.x & 0x1FFFF];
        float v2 = __int_as_float(p2.y) * wc[p2.x & 0x1FFFF];
        float v3 = __int_as_float(p3.y) * wc[p3.x & 0x1FFFF];
        if (v0 != 0.f) atomicAdd(&acc[p0.x >> 17], v0);
        if (v1 != 0.f) atomicAdd(&acc[p1.x >> 17], v1);
        if (v2 != 0.f) atomicAdd(&acc[p2.x >> 17], v2);
        if (v3 != 0.f) atomicAdd(&acc[p3.x >> 17], v3);
    }
    for (; i < mye; i += 256) {
        int2 p = packed[i];
        float v = __int_as_float(p.y) * wc[p.x & 0x1FFFF];
        if (v != 0.f) atomicAdd(&acc[p.x >> 17], v);
    }
    __syncthreads();
    #pragma unroll
    for (int k = 0; k < 4; ++k) {
        int row = bucket * RPB + t + 256 * k;
        float a = acc[t + 256 * k];
        if (a != 0.f && row < NN) atomicAdd(&wn[row], a);
    }
}

// tiled final dot: 196 blocks x 512-row tiles
__global__ void final_dot(const float* __restrict__ x, const float* __restrict__ tw,
                          const float* __restrict__ tb, const int* __restrict__ ct,
                          const float* __restrict__ u,
                          float* __restrict__ acc_out) {
    __shared__ float s[512];
    __shared__ float sred[256][4];
    __shared__ float sbias[4];
    int tid = threadIdx.x;          // 256
    int base = blockIdx.x * 512;
    int nrows = min(512, NN - base);
    float accb = 0.f;
    for (int r = tid; r < nrows; r += 256) {
        int n = base + r;
        float un = u[n];
        int t = ct[n];
        s[r] = un * tw[t];
        accb = fmaf(un, tb[t], accb);
    }
    __syncthreads();
    float a0 = 0.f, a1 = 0.f, a2 = 0.f, a3 = 0.f;
    int j = (tid & 3) * 4;
    for (int r = tid >> 2; r < nrows; r += 64) {
        float4 xv = *(const float4*)&x[(size_t)(base + r) * NB + j];
        float sv = s[r];
        a0 = fmaf(sv, xv.x, a0);
        a1 = fmaf(sv, xv.y, a1);
        a2 = fmaf(sv, xv.z, a2);
        a3 = fmaf(sv, xv.w, a3);
    }
    sred[tid][0] = a0; sred[tid][1] = a1; sred[tid][2] = a2; sred[tid][3] = a3;
    for (int off = 32; off; off >>= 1) accb += __shfl_down(accb, off);
    if ((tid & 63) == 0) sbias[tid >> 6] = accb;
    __syncthreads();
    if (tid < 16) {
        int q = tid >> 2, k = tid & 3;
        float sum = 0.f;
        for (int i = 0; i < 64; ++i) sum += sred[q + 4 * i][k];
        atomicAdd(&acc_out[tid], sum);
    }
    if (tid == 16)
        atomicAdd(&acc_out[16], sbias[0] + sbias[1] + sbias[2] + sbias[3]);
}

__global__ void finalize(const float* __restrict__ acc, const float* __restrict__ fcb,
                         float* __restrict__ out) {
    int b = threadIdx.x;
    if (b < NB) out[b] = acc[b] + acc[16] + fcb[0];
}

extern "C" void kernel_launch(void* const* d_in, const int* in_sizes, int n_in,
                              void* d_out, int out_size, void* d_ws, size_t ws_size,
                              hipStream_t stream) {
    const float* x   = (const float*)d_in[0];
    const float* tw  = (const float*)d_in[1];
    const float* tb  = (const float*)d_in[2];
    const float* ew  = (const float*)d_in[3];
    const float* dmv = (const float*)d_in[4];
    const float* fcw = (const float*)d_in[5];
    const float* fcb = (const float*)d_in[6];
    const int* ct  = (const int*)d_in[7];
    const int* er  = (const int*)d_in[8];
    const int* ec  = (const int*)d_in[9];
    const int* dmc = (const int*)d_in[10];
    float* out = (float*)d_out;

    // ws: [zero-region: u0..u4 (5*NN) | acc(32)] cursor(128) packed(98*CAP*8 = 43.4MB)
    char* ws = (char*)d_ws;
    float* u   = (float*)ws;                       // u + k*NN, k=0..4
    float* acc = u + 5 * (size_t)NN;
    size_t zero_bytes = (5 * (size_t)NN + 32) * 4;
    ws += zero_bytes;
    int* cursor = (int*)ws;         ws += 128 * 4;
    ws = (char*)(((uintptr_t)ws + 15) & ~(uintptr_t)15);
    int2* packed = (int2*)ws;       // NBUCKET * CAP * 8B

    // zero all hop buffers + acc (cursor is set by setup)
    hipMemsetAsync(u, 0, zero_bytes, stream);

    // u0 = v; cursor[b] = b*CAP
    setup<<<1, 512, 0, stream>>>(dmv, dmc, fcw, u, cursor);

    // one pass over edges: bucket-sort into packed + fused hop 1 (u0 -> u1)
    scatter_fused<<<NCHUNK, 1024, 0, stream>>>(er, ec, ew, u, u + NN, cursor, packed);

    // hops 2..4 on sorted packed edges
    for (int l = 1; l < 4; ++l) {
        spmv_sorted<<<NBUCKET * SUB, 256, 0, stream>>>(cursor, packed,
                                                       u + (size_t)l * NN,
                                                       u + (size_t)(l + 1) * NN);
    }

    // out[b] = sum_n u4[n]*(tw[ct[n]]*x[n,b] + tb[ct[n]]) + fcb
    final_dot<<<(NN + 511) / 512, 256, 0, stream>>>(x, tw, tb, ct, u + 4 * (size_t)NN, acc);
    finalize<<<1, 64, 0, stream>>>(acc, fcb, out);
}